// Round 3
// baseline (1173.253 us; speedup 1.0000x reference)
//
#include <hip/hip_runtime.h>

#define NN 50000
#define NE 800000
#define NL 3

typedef __bf16 bf16x8 __attribute__((ext_vector_type(8)));
typedef float f32x16 __attribute__((ext_vector_type(16)));
typedef unsigned int u32x4 __attribute__((ext_vector_type(4)));

// ---------------- degree histogram ----------------
__global__ __launch_bounds__(256) void k_deg(const int* __restrict__ trg,
                                             float* __restrict__ deg) {
  int e = blockIdx.x * 256 + threadIdx.x;
  if (e < NE) atomicAdd(&deg[trg[e]], 1.0f);
}

// ---------------- exclusive scan of degrees -> CSR row starts ----------------
__global__ __launch_bounds__(1024) void k_scan(const float* __restrict__ deg,
                                               int* __restrict__ rowstart,
                                               int* __restrict__ cursor) {
  __shared__ int part[1024];
  int t = threadIdx.x;
  int t0 = t * 49, t1 = min(t0 + 49, NN);
  int s = 0;
  for (int i = t0; i < t1; i++) s += (int)deg[i];
  part[t] = s;
  __syncthreads();
  for (int off = 1; off < 1024; off <<= 1) {
    int vv = (t >= off) ? part[t - off] : 0;
    int v = part[t];
    __syncthreads();
    part[t] = v + vv;
    __syncthreads();
  }
  int run = part[t] - s;  // exclusive prefix
  for (int i = t0; i < t1; i++) {
    rowstart[i] = run;
    cursor[i] = run;
    run += (int)deg[i];
  }
  if (t == 1023) rowstart[NN] = NE;
}

// ---------------- CSR fill: bucket src ids by trg ----------------
__global__ __launch_bounds__(256) void k_fill(const int* __restrict__ src,
                                              const int* __restrict__ trg,
                                              int* __restrict__ cursor,
                                              int* __restrict__ csr) {
  int e = blockIdx.x * 256 + threadIdx.x;
  if (e < NE) {
    int pos = atomicAdd(&cursor[trg[e]], 1);
    csr[pos] = src[e];
  }
}

// ---------------- gather aggregation (mean, deg-division folded) ----------------
__global__ __launch_bounds__(256) void k_agg(const float* __restrict__ x,
                                             const int* __restrict__ rowstart,
                                             const int* __restrict__ csr,
                                             float* __restrict__ agg, int relu) {
  int i = blockIdx.x * 256 + threadIdx.x;
  int n = i >> 4, q = i & 15;
  const float4* x4 = (const float4*)x;
  int b = rowstart[n], en = rowstart[n + 1];
  float4 v = make_float4(0.f, 0.f, 0.f, 0.f);
  for (int j = b; j < en; j++) {
    float4 a = x4[(size_t)csr[j] * 16 + q];
    if (relu) {
      a.x = fmaxf(a.x, 0.f); a.y = fmaxf(a.y, 0.f);
      a.z = fmaxf(a.z, 0.f); a.w = fmaxf(a.w, 0.f);
    }
    v.x += a.x; v.y += a.y; v.z += a.z; v.w += a.w;
  }
  float inv = 1.0f / fmaxf((float)(en - b), 1.0f);
  v.x *= inv; v.y *= inv; v.z *= inv; v.w *= inv;
  ((float4*)agg)[(size_t)n * 16 + q] = v;
}

// ---------------- node conv: xout = relu?(x)@Ws + agg@Wn + b (+ bf16 mirror) ----------------
__global__ __launch_bounds__(256) void k_conv(const float* __restrict__ x,
                                              const float* __restrict__ agg,
                                              const float* __restrict__ Ws,
                                              const float* __restrict__ Wn,
                                              const float* __restrict__ bc,
                                              float* __restrict__ xout,
                                              unsigned short* __restrict__ xb,
                                              int relu) {
  __shared__ float sWs[64 * 64];
  __shared__ float sWn[64 * 64];
  __shared__ float sx[4][64];
  __shared__ float sa[4][64];
  int tid = threadIdx.x;
  for (int i = tid; i < 4096; i += 256) { sWs[i] = Ws[i]; sWn[i] = Wn[i]; }
  int g = tid >> 6, lane = tid & 63;
  int n = blockIdx.x * 4 + g;
  float xv = x[(size_t)n * 64 + lane];
  if (relu) xv = fmaxf(xv, 0.f);
  sx[g][lane] = xv;
  sa[g][lane] = agg[(size_t)n * 64 + lane];
  __syncthreads();
  float acc = bc[lane];
  #pragma unroll
  for (int k = 0; k < 64; k++) {
    acc += sx[g][k] * sWs[k * 64 + lane] + sa[g][k] * sWn[k * 64 + lane];
  }
  xout[(size_t)n * 64 + lane] = acc;
  xb[(size_t)n * 64 + lane] = __builtin_bit_cast(unsigned short, (__bf16)acc);
}

// ---------------- W_fc prep into MFMA-B LDS layout ----------------
// Wt2[l][ks][kg][col][e] = bf16(W_fc[l][ks*16+kg*8+e][col]); 16*2*64*8 = 16K
// ushorts = 32KB per layer. k_edge block-copies this linearly into LDS; the
// B-frag ds_read for (ks,kg,col) is then a contiguous 1KB/wave access
// (conflict-free).
__global__ __launch_bounds__(256) void k_wprep(const float* __restrict__ Wfc,
                                               unsigned short* __restrict__ Wt) {
  int idx = blockIdx.x * 256 + threadIdx.x;   // [0, 3*16384)
  int l = idx >> 14;
  int o = idx & 16383;
  int e = o & 7;
  int col = (o >> 3) & 63;
  int kg = (o >> 9) & 1;
  int ks = o >> 10;
  int k = ks * 16 + kg * 8 + e;
  float v = Wfc[((size_t)l * 257 + k) * 64 + col];
  Wt[idx] = __builtin_bit_cast(unsigned short, (__bf16)v);
}

__device__ inline u32x4 pack8(const float* f) {
  u32x4 r;
  #pragma unroll
  for (int i = 0; i < 4; i++) {
    unsigned short lo = __builtin_bit_cast(unsigned short, (__bf16)f[2 * i]);
    unsigned short hi = __builtin_bit_cast(unsigned short, (__bf16)f[2 * i + 1]);
    r[i] = (unsigned)lo | ((unsigned)hi << 16);
  }
  return r;
}

__device__ inline float bflo(unsigned u) {
  return __builtin_bit_cast(float, u << 16);
}
__device__ inline float bfhi(unsigned u) {
  return __builtin_bit_cast(float, u & 0xffff0000u);
}

// ---------------- edge update v7: Wt in LDS (kills divergent B-reads) ----------------
// Theory: k_edge is bound by TA/L1 divergent-address processing, not bytes.
// Per wave, the global Wt B-frag reads were 32 instr x 32 cache lines = 1024
// divergent lines (70% of all line-transactions). Stage Wt (32KB) in LDS once
// per block (coalesced, one barrier), read frags via ds_read_b128 (LDS pipe,
// conflict-free layout). Grid-stride over tiles amortizes staging; waves stay
// independent (no in-loop barriers). x from bf16 mirror; sim from bf16-rounded
// values; sim*w256 folded post-MFMA.
template <int IN_BF16, int OUT_BF16>
__global__ __launch_bounds__(256, 4) void k_edge(
    const unsigned short* __restrict__ xb, const int* __restrict__ src,
    const int* __restrict__ trg, const void* ef_in,
    const unsigned short* __restrict__ Wt, const float* __restrict__ w256,
    const float* __restrict__ bfc, void* ef_out) {
  __shared__ __align__(16) unsigned short sB[16384];  // 32KB: [ks][kg][col][8]

  int t = threadIdx.x;
  // ---- stage Wt -> LDS (linear, coalesced) ----
  {
    const u32x4* wg = (const u32x4*)Wt;
    u32x4* sb = (u32x4*)sB;
    #pragma unroll
    for (int i = 0; i < 8; i++) sb[t + 256 * i] = wg[t + 256 * i];
  }
  __syncthreads();
  const u32x4* sb4 = (const u32x4*)sB;

  int w = t >> 6;
  int lane = t & 63;
  int rl = lane & 31;   // edge within tile == MFMA row == output col offset
  int kg = lane >> 5;   // k-half
  int col0 = rl, col1 = 32 + rl;
  float wv0 = w256[col0], wv1 = w256[col1];
  float b0 = bfc[col0], b1 = bfc[col1];

  int gw = blockIdx.x * 4 + w;
  int nw = gridDim.x * 4;
  const u32x4* xq = (const u32x4*)xb;

  for (int tile = gw; tile < NE / 32; tile += nw) {
    int e0 = tile * 32;
    int e = e0 + rl;
    int se = src[e], te = trg[e];

    // ---- issue ef load first ----
    u32x4 efr[4];
    if (IN_BF16) {
      const u32x4* eb = (const u32x4*)ef_in;
      #pragma unroll
      for (int j = 0; j < 4; j++) efr[j] = eb[(size_t)e * 8 + j * 2 + kg];
    } else {
      const float4* ef4 = (const float4*)ef_in;
      #pragma unroll
      for (int j = 0; j < 4; j++) {
        float4 a = ef4[(size_t)e * 16 + j * 4 + kg * 2];
        float4 b = ef4[(size_t)e * 16 + j * 4 + kg * 2 + 1];
        float f[8] = {a.x, a.y, a.z, a.w, b.x, b.y, b.z, b.w};
        efr[j] = pack8(f);
      }
    }

    // ---- issue x gathers (random bf16 128B rows) ----
    u32x4 sfr[4], tfr[4];
    #pragma unroll
    for (int j = 0; j < 4; j++) {
      sfr[j] = xq[(size_t)se * 8 + j * 2 + kg];
      tfr[j] = xq[(size_t)te * 8 + j * 2 + kg];
    }

    f32x16 acc0, acc1;
    #pragma unroll
    for (int r = 0; r < 16; r++) { acc0[r] = b0; acc1[r] = b1; }

    // ---- ef MFMAs (k 0..63): overlap x-gather latency ----
    #pragma unroll
    for (int ks = 0; ks < 4; ks++) {
      bf16x8 av = __builtin_bit_cast(bf16x8, efr[ks]);
      int bi = (ks * 2 + kg) * 64;
      acc0 = __builtin_amdgcn_mfma_f32_32x32x16_bf16(
          av, __builtin_bit_cast(bf16x8, sb4[bi + col0]), acc0, 0, 0, 0);
      acc1 = __builtin_amdgcn_mfma_f32_32x32x16_bf16(
          av, __builtin_bit_cast(bf16x8, sb4[bi + col1]), acc1, 0, 0, 0);
    }
    // ---- xs MFMAs (k 64..127) ----
    #pragma unroll
    for (int ks = 4; ks < 8; ks++) {
      bf16x8 av = __builtin_bit_cast(bf16x8, sfr[ks - 4]);
      int bi = (ks * 2 + kg) * 64;
      acc0 = __builtin_amdgcn_mfma_f32_32x32x16_bf16(
          av, __builtin_bit_cast(bf16x8, sb4[bi + col0]), acc0, 0, 0, 0);
      acc1 = __builtin_amdgcn_mfma_f32_32x32x16_bf16(
          av, __builtin_bit_cast(bf16x8, sb4[bi + col1]), acc1, 0, 0, 0);
    }
    // ---- xt MFMAs (k 128..191) ----
    #pragma unroll
    for (int ks = 8; ks < 12; ks++) {
      bf16x8 av = __builtin_bit_cast(bf16x8, tfr[ks - 8]);
      int bi = (ks * 2 + kg) * 64;
      acc0 = __builtin_amdgcn_mfma_f32_32x32x16_bf16(
          av, __builtin_bit_cast(bf16x8, sb4[bi + col0]), acc0, 0, 0, 0);
      acc1 = __builtin_amdgcn_mfma_f32_32x32x16_bf16(
          av, __builtin_bit_cast(bf16x8, sb4[bi + col1]), acc1, 0, 0, 0);
    }

    // ---- sim partials + |xs-xt| frags (from bf16-rounded values) ----
    float dot = 0.f, n1 = 0.f, n2 = 0.f;
    u32x4 dfr[4];
    #pragma unroll
    for (int j = 0; j < 4; j++) {
      float fs[8], ft[8], fd[8];
      #pragma unroll
      for (int q = 0; q < 4; q++) {
        fs[2 * q] = bflo(sfr[j][q]); fs[2 * q + 1] = bfhi(sfr[j][q]);
        ft[2 * q] = bflo(tfr[j][q]); ft[2 * q + 1] = bfhi(tfr[j][q]);
      }
      #pragma unroll
      for (int c = 0; c < 8; c++) {
        dot = fmaf(fs[c], ft[c], dot);
        n1 = fmaf(fs[c], fs[c], n1);
        n2 = fmaf(ft[c], ft[c], n2);
        fd[c] = fabsf(fs[c] - ft[c]);
      }
      dfr[j] = pack8(fd);
    }

    // ---- |xs-xt| MFMAs (k 192..255) ----
    #pragma unroll
    for (int ks = 12; ks < 16; ks++) {
      bf16x8 av = __builtin_bit_cast(bf16x8, dfr[ks - 12]);
      int bi = (ks * 2 + kg) * 64;
      acc0 = __builtin_amdgcn_mfma_f32_32x32x16_bf16(
          av, __builtin_bit_cast(bf16x8, sb4[bi + col0]), acc0, 0, 0, 0);
      acc1 = __builtin_amdgcn_mfma_f32_32x32x16_bf16(
          av, __builtin_bit_cast(bf16x8, sb4[bi + col1]), acc1, 0, 0, 0);
    }

    // ---- combine kg-halves -> sim; fold sim-column (k=256) into output ----
    dot += __shfl_xor(dot, 32);
    n1 += __shfl_xor(n1, 32);
    n2 += __shfl_xor(n2, 32);
    float sim = dot / fmaxf(sqrtf(n1) * sqrtf(n2), 1e-8f);

    // ---- store C (bf16 inter-layer, fp32 final) ----
    #pragma unroll
    for (int r = 0; r < 16; r++) {
      int row = (r & 3) + 8 * (r >> 2) + 4 * kg;
      float s = __shfl(sim, row);
      float o0 = fmaf(s, wv0, acc0[r]);
      float o1 = fmaf(s, wv1, acc1[r]);
      size_t base = (size_t)(e0 + row) * 64;
      if (OUT_BF16) {
        unsigned short* ob = (unsigned short*)ef_out;
        ob[base + col0] = __builtin_bit_cast(unsigned short, (__bf16)o0);
        ob[base + col1] = __builtin_bit_cast(unsigned short, (__bf16)o1);
      } else {
        float* of = (float*)ef_out;
        of[base + col0] = o0;
        of[base + col1] = o1;
      }
    }
  }
}

extern "C" void kernel_launch(void* const* d_in, const int* in_sizes, int n_in,
                              void* d_out, int out_size, void* d_ws, size_t ws_size,
                              hipStream_t stream) {
  const float* x_in   = (const float*)d_in[0];
  const int*   ei     = (const int*)d_in[1];
  const float* ef_in  = (const float*)d_in[2];
  const float* W_self = (const float*)d_in[3];
  const float* W_nbr  = (const float*)d_in[4];
  const float* b_conv = (const float*)d_in[5];
  const float* W_fc   = (const float*)d_in[6];
  const float* b_fc   = (const float*)d_in[7];
  float* out = (float*)d_out;

  const int* src = ei;
  const int* trg = ei + NE;

  char* ws = (char*)d_ws;
  size_t off = 0;
  float* deg      = (float*)(ws + off); off += (((size_t)NN * 4) + 255) & ~(size_t)255;
  int*   rowstart = (int*)(ws + off);   off += (((size_t)(NN + 1) * 4) + 255) & ~(size_t)255;
  int*   cursor   = (int*)(ws + off);   off += (((size_t)NN * 4) + 255) & ~(size_t)255;
  int*   csr      = (int*)(ws + off);   off += (size_t)NE * 4;
  float* agg      = (float*)(ws + off); off += (size_t)NN * 64 * 4;
  float* x_a      = (float*)(ws + off); off += (size_t)NN * 64 * 4;
  float* x_b      = (float*)(ws + off); off += (size_t)NN * 64 * 4;
  unsigned short* Wt  = (unsigned short*)(ws + off); off += (size_t)NL * 64 * 256 * 2;
  unsigned short* efb = (unsigned short*)(ws + off); off += (size_t)NE * 64 * 2;
  unsigned short* xbm = (unsigned short*)(ws + off); off += (size_t)NN * 64 * 2;

  hipMemsetAsync(deg, 0, (size_t)NN * 4, stream);
  k_deg<<<(NE + 255) / 256, 256, 0, stream>>>(trg, deg);
  k_scan<<<1, 1024, 0, stream>>>(deg, rowstart, cursor);
  k_fill<<<(NE + 255) / 256, 256, 0, stream>>>(src, trg, cursor, csr);
  k_wprep<<<(NL * 16384) / 256, 256, 0, stream>>>(W_fc, Wt);

  const float* xcur = x_in;
  float* xnext = x_a;

  for (int i = 0; i < NL; i++) {
    int relu = (i > 0) ? 1 : 0;
    k_agg<<<(NN * 16) / 256, 256, 0, stream>>>(xcur, rowstart, csr, agg, relu);
    k_conv<<<NN / 4, 256, 0, stream>>>(xcur, agg,
                                       W_self + (size_t)i * 4096,
                                       W_nbr + (size_t)i * 4096,
                                       b_conv + (size_t)i * 64,
                                       xnext, xbm, relu);
    const unsigned short* Wti = Wt + (size_t)i * 16384;
    const float* w256 = W_fc + ((size_t)i * 257 + 256) * 64;
    const float* bfc = b_fc + (size_t)i * 64;
    if (i == 0) {
      k_edge<0, 1><<<1024, 256, 0, stream>>>(xbm, src, trg, ef_in,
                                             Wti, w256, bfc, efb);
    } else if (i == 1) {
      k_edge<1, 1><<<1024, 256, 0, stream>>>(xbm, src, trg, efb,
                                             Wti, w256, bfc, efb);
    } else {
      k_edge<1, 0><<<1024, 256, 0, stream>>>(xbm, src, trg, efb,
                                             Wti, w256, bfc, out);
    }
    xcur = xnext;
    xnext = (xnext == x_a) ? x_b : x_a;
  }
}

// Round 4
// 753.284 us; speedup vs baseline: 1.5575x; 1.5575x over previous
//
#include <hip/hip_runtime.h>

#define NN 50000
#define NE 800000
#define NL 3

typedef __bf16 bf16x8 __attribute__((ext_vector_type(8)));
typedef float f32x16 __attribute__((ext_vector_type(16)));
typedef unsigned int u32x4 __attribute__((ext_vector_type(4)));

// ---------------- degree histogram ----------------
__global__ __launch_bounds__(256) void k_deg(const int* __restrict__ trg,
                                             float* __restrict__ deg) {
  int e = blockIdx.x * 256 + threadIdx.x;
  if (e < NE) atomicAdd(&deg[trg[e]], 1.0f);
}

// ---------------- exclusive scan of degrees -> CSR row starts ----------------
__global__ __launch_bounds__(1024) void k_scan(const float* __restrict__ deg,
                                               int* __restrict__ rowstart,
                                               int* __restrict__ cursor) {
  __shared__ int part[1024];
  int t = threadIdx.x;
  int t0 = t * 49, t1 = min(t0 + 49, NN);
  int s = 0;
  for (int i = t0; i < t1; i++) s += (int)deg[i];
  part[t] = s;
  __syncthreads();
  for (int off = 1; off < 1024; off <<= 1) {
    int vv = (t >= off) ? part[t - off] : 0;
    int v = part[t];
    __syncthreads();
    part[t] = v + vv;
    __syncthreads();
  }
  int run = part[t] - s;  // exclusive prefix
  for (int i = t0; i < t1; i++) {
    rowstart[i] = run;
    cursor[i] = run;
    run += (int)deg[i];
  }
  if (t == 1023) rowstart[NN] = NE;
}

// ---------------- CSR fill: bucket src ids by trg ----------------
__global__ __launch_bounds__(256) void k_fill(const int* __restrict__ src,
                                              const int* __restrict__ trg,
                                              int* __restrict__ cursor,
                                              int* __restrict__ csr) {
  int e = blockIdx.x * 256 + threadIdx.x;
  if (e < NE) {
    int pos = atomicAdd(&cursor[trg[e]], 1);
    csr[pos] = src[e];
  }
}

// ---------------- gather aggregation (mean, deg-division folded) ----------------
__global__ __launch_bounds__(256) void k_agg(const float* __restrict__ x,
                                             const int* __restrict__ rowstart,
                                             const int* __restrict__ csr,
                                             float* __restrict__ agg, int relu) {
  int i = blockIdx.x * 256 + threadIdx.x;
  int n = i >> 4, q = i & 15;
  const float4* x4 = (const float4*)x;
  int b = rowstart[n], en = rowstart[n + 1];
  float4 v = make_float4(0.f, 0.f, 0.f, 0.f);
  for (int j = b; j < en; j++) {
    float4 a = x4[(size_t)csr[j] * 16 + q];
    if (relu) {
      a.x = fmaxf(a.x, 0.f); a.y = fmaxf(a.y, 0.f);
      a.z = fmaxf(a.z, 0.f); a.w = fmaxf(a.w, 0.f);
    }
    v.x += a.x; v.y += a.y; v.z += a.z; v.w += a.w;
  }
  float inv = 1.0f / fmaxf((float)(en - b), 1.0f);
  v.x *= inv; v.y *= inv; v.z *= inv; v.w *= inv;
  ((float4*)agg)[(size_t)n * 16 + q] = v;
}

// ---------------- node conv: xout = relu?(x)@Ws + agg@Wn + b (+ bf16 mirror) ----------------
__global__ __launch_bounds__(256) void k_conv(const float* __restrict__ x,
                                              const float* __restrict__ agg,
                                              const float* __restrict__ Ws,
                                              const float* __restrict__ Wn,
                                              const float* __restrict__ bc,
                                              float* __restrict__ xout,
                                              unsigned short* __restrict__ xb,
                                              int relu) {
  __shared__ float sWs[64 * 64];
  __shared__ float sWn[64 * 64];
  __shared__ float sx[4][64];
  __shared__ float sa[4][64];
  int tid = threadIdx.x;
  for (int i = tid; i < 4096; i += 256) { sWs[i] = Ws[i]; sWn[i] = Wn[i]; }
  int g = tid >> 6, lane = tid & 63;
  int n = blockIdx.x * 4 + g;
  float xv = x[(size_t)n * 64 + lane];
  if (relu) xv = fmaxf(xv, 0.f);
  sx[g][lane] = xv;
  sa[g][lane] = agg[(size_t)n * 64 + lane];
  __syncthreads();
  float acc = bc[lane];
  #pragma unroll
  for (int k = 0; k < 64; k++) {
    acc += sx[g][k] * sWs[k * 64 + lane] + sa[g][k] * sWn[k * 64 + lane];
  }
  xout[(size_t)n * 64 + lane] = acc;
  xb[(size_t)n * 64 + lane] = __builtin_bit_cast(unsigned short, (__bf16)acc);
}

// ---------------- W_fc prep into MFMA-B LDS layout ----------------
// Wt2[l][ks][kg][col][e] = bf16(W_fc[l][ks*16+kg*8+e][col]); 16*2*64*8 = 16K
// ushorts = 32KB per layer. k_edge block-copies this linearly into LDS; the
// B-frag ds_read for (ks,kg,col) is then a contiguous 1KB/wave access
// (conflict-free).
__global__ __launch_bounds__(256) void k_wprep(const float* __restrict__ Wfc,
                                               unsigned short* __restrict__ Wt) {
  int idx = blockIdx.x * 256 + threadIdx.x;   // [0, 3*16384)
  int l = idx >> 14;
  int o = idx & 16383;
  int e = o & 7;
  int col = (o >> 3) & 63;
  int kg = (o >> 9) & 1;
  int ks = o >> 10;
  int k = ks * 16 + kg * 8 + e;
  float v = Wfc[((size_t)l * 257 + k) * 64 + col];
  Wt[idx] = __builtin_bit_cast(unsigned short, (__bf16)v);
}

__device__ inline u32x4 pack8(const float* f) {
  u32x4 r;
  #pragma unroll
  for (int i = 0; i < 4; i++) {
    unsigned short lo = __builtin_bit_cast(unsigned short, (__bf16)f[2 * i]);
    unsigned short hi = __builtin_bit_cast(unsigned short, (__bf16)f[2 * i + 1]);
    r[i] = (unsigned)lo | ((unsigned)hi << 16);
  }
  return r;
}

__device__ inline float bflo(unsigned u) {
  return __builtin_bit_cast(float, u << 16);
}
__device__ inline float bfhi(unsigned u) {
  return __builtin_bit_cast(float, u & 0xffff0000u);
}

// ---------------- edge update v8: R2 structure + Wt in LDS (single change) ----------------
// R0-R2 were pinned at ~225us regardless of traffic (482/390/372 MB): the
// invariant component is the Wt B-frag read pattern -- 32 instrs x 32
// 512B-strided lines = 1024 L2 requests per wave = 25.6M/dispatch (~75% of
// all L2 requests). Theory: aggregate L2 request throughput is the binding
// pipe. Fix: stage Wt (32KB) into LDS once per block (coalesced, one initial
// barrier), read B-frags via conflict-free ds_read_b128. Everything else
// (tile ownership, gather/store patterns, grid) is byte-identical to R2 --
// contiguous mapping, one tile per wave, no in-loop barriers.
template <int IN_BF16, int OUT_BF16>
__global__ __launch_bounds__(256, 4) void k_edge(
    const unsigned short* __restrict__ xb, const int* __restrict__ src,
    const int* __restrict__ trg, const void* ef_in,
    const unsigned short* __restrict__ Wt, const float* __restrict__ w256,
    const float* __restrict__ bfc, void* ef_out) {
  __shared__ __align__(16) unsigned short sB[16384];  // 32KB: [ks][kg][col][8]

  int t = threadIdx.x;
  // ---- stage Wt -> LDS (linear, coalesced, L2-hot) ----
  {
    const u32x4* wg = (const u32x4*)Wt;
    u32x4* sb = (u32x4*)sB;
    #pragma unroll
    for (int i = 0; i < 8; i++) sb[t + 256 * i] = wg[t + 256 * i];
  }
  __syncthreads();
  const u32x4* sb4 = (const u32x4*)sB;

  int w = t >> 6;
  int lane = t & 63;
  int rl = lane & 31;   // edge within tile == MFMA row == output col offset
  int kg = lane >> 5;   // k-half
  int e0 = (blockIdx.x * 4 + w) * 32;
  int e = e0 + rl;

  int se = src[e], te = trg[e];

  // ---- issue ef load first (streaming) ----
  u32x4 efr[4];
  if (IN_BF16) {
    const u32x4* eb = (const u32x4*)ef_in;
    #pragma unroll
    for (int j = 0; j < 4; j++) efr[j] = eb[(size_t)e * 8 + j * 2 + kg];
  } else {
    const float4* ef4 = (const float4*)ef_in;
    #pragma unroll
    for (int j = 0; j < 4; j++) {
      float4 a = ef4[(size_t)e * 16 + j * 4 + kg * 2];
      float4 b = ef4[(size_t)e * 16 + j * 4 + kg * 2 + 1];
      float f[8] = {a.x, a.y, a.z, a.w, b.x, b.y, b.z, b.w};
      efr[j] = pack8(f);
    }
  }

  // ---- issue x gathers (random bf16 128B rows) ----
  const u32x4* xq = (const u32x4*)xb;
  u32x4 sfr[4], tfr[4];
  #pragma unroll
  for (int j = 0; j < 4; j++) {
    sfr[j] = xq[(size_t)se * 8 + j * 2 + kg];
    tfr[j] = xq[(size_t)te * 8 + j * 2 + kg];
  }

  int col0 = rl, col1 = 32 + rl;
  float wv0 = w256[col0], wv1 = w256[col1];
  f32x16 acc0, acc1;
  {
    float b0 = bfc[col0], b1 = bfc[col1];
    #pragma unroll
    for (int r = 0; r < 16; r++) { acc0[r] = b0; acc1[r] = b1; }
  }

  // ---- ef MFMAs (k 0..63): overlap x-gather latency ----
  #pragma unroll
  for (int ks = 0; ks < 4; ks++) {
    bf16x8 av = __builtin_bit_cast(bf16x8, efr[ks]);
    int bi = (ks * 2 + kg) * 64;
    acc0 = __builtin_amdgcn_mfma_f32_32x32x16_bf16(
        av, __builtin_bit_cast(bf16x8, sb4[bi + col0]), acc0, 0, 0, 0);
    acc1 = __builtin_amdgcn_mfma_f32_32x32x16_bf16(
        av, __builtin_bit_cast(bf16x8, sb4[bi + col1]), acc1, 0, 0, 0);
  }
  // ---- xs MFMAs (k 64..127) ----
  #pragma unroll
  for (int ks = 4; ks < 8; ks++) {
    bf16x8 av = __builtin_bit_cast(bf16x8, sfr[ks - 4]);
    int bi = (ks * 2 + kg) * 64;
    acc0 = __builtin_amdgcn_mfma_f32_32x32x16_bf16(
        av, __builtin_bit_cast(bf16x8, sb4[bi + col0]), acc0, 0, 0, 0);
    acc1 = __builtin_amdgcn_mfma_f32_32x32x16_bf16(
        av, __builtin_bit_cast(bf16x8, sb4[bi + col1]), acc1, 0, 0, 0);
  }
  // ---- xt MFMAs (k 128..191) ----
  #pragma unroll
  for (int ks = 8; ks < 12; ks++) {
    bf16x8 av = __builtin_bit_cast(bf16x8, tfr[ks - 8]);
    int bi = (ks * 2 + kg) * 64;
    acc0 = __builtin_amdgcn_mfma_f32_32x32x16_bf16(
        av, __builtin_bit_cast(bf16x8, sb4[bi + col0]), acc0, 0, 0, 0);
    acc1 = __builtin_amdgcn_mfma_f32_32x32x16_bf16(
        av, __builtin_bit_cast(bf16x8, sb4[bi + col1]), acc1, 0, 0, 0);
  }

  // ---- sim partials + |xs-xt| frags (from bf16-rounded values) ----
  float dot = 0.f, n1 = 0.f, n2 = 0.f;
  u32x4 dfr[4];
  #pragma unroll
  for (int j = 0; j < 4; j++) {
    float fs[8], ft[8], fd[8];
    #pragma unroll
    for (int q = 0; q < 4; q++) {
      fs[2 * q] = bflo(sfr[j][q]); fs[2 * q + 1] = bfhi(sfr[j][q]);
      ft[2 * q] = bflo(tfr[j][q]); ft[2 * q + 1] = bfhi(tfr[j][q]);
    }
    #pragma unroll
    for (int c = 0; c < 8; c++) {
      dot = fmaf(fs[c], ft[c], dot);
      n1 = fmaf(fs[c], fs[c], n1);
      n2 = fmaf(ft[c], ft[c], n2);
      fd[c] = fabsf(fs[c] - ft[c]);
    }
    dfr[j] = pack8(fd);
  }

  // ---- |xs-xt| MFMAs (k 192..255) ----
  #pragma unroll
  for (int ks = 12; ks < 16; ks++) {
    bf16x8 av = __builtin_bit_cast(bf16x8, dfr[ks - 12]);
    int bi = (ks * 2 + kg) * 64;
    acc0 = __builtin_amdgcn_mfma_f32_32x32x16_bf16(
        av, __builtin_bit_cast(bf16x8, sb4[bi + col0]), acc0, 0, 0, 0);
    acc1 = __builtin_amdgcn_mfma_f32_32x32x16_bf16(
        av, __builtin_bit_cast(bf16x8, sb4[bi + col1]), acc1, 0, 0, 0);
  }

  // ---- combine kg-halves -> sim; fold sim-column (k=256) into output ----
  dot += __shfl_xor(dot, 32);
  n1 += __shfl_xor(n1, 32);
  n2 += __shfl_xor(n2, 32);
  float sim = dot / fmaxf(sqrtf(n1) * sqrtf(n2), 1e-8f);

  // ---- store C (bf16 inter-layer, fp32 final) ----
  #pragma unroll
  for (int r = 0; r < 16; r++) {
    int row = (r & 3) + 8 * (r >> 2) + 4 * kg;
    float s = __shfl(sim, row);
    float o0 = fmaf(s, wv0, acc0[r]);
    float o1 = fmaf(s, wv1, acc1[r]);
    size_t base = (size_t)(e0 + row) * 64;
    if (OUT_BF16) {
      unsigned short* ob = (unsigned short*)ef_out;
      ob[base + col0] = __builtin_bit_cast(unsigned short, (__bf16)o0);
      ob[base + col1] = __builtin_bit_cast(unsigned short, (__bf16)o1);
    } else {
      float* of = (float*)ef_out;
      of[base + col0] = o0;
      of[base + col1] = o1;
    }
  }
}

extern "C" void kernel_launch(void* const* d_in, const int* in_sizes, int n_in,
                              void* d_out, int out_size, void* d_ws, size_t ws_size,
                              hipStream_t stream) {
  const float* x_in   = (const float*)d_in[0];
  const int*   ei     = (const int*)d_in[1];
  const float* ef_in  = (const float*)d_in[2];
  const float* W_self = (const float*)d_in[3];
  const float* W_nbr  = (const float*)d_in[4];
  const float* b_conv = (const float*)d_in[5];
  const float* W_fc   = (const float*)d_in[6];
  const float* b_fc   = (const float*)d_in[7];
  float* out = (float*)d_out;

  const int* src = ei;
  const int* trg = ei + NE;

  char* ws = (char*)d_ws;
  size_t off = 0;
  float* deg      = (float*)(ws + off); off += (((size_t)NN * 4) + 255) & ~(size_t)255;
  int*   rowstart = (int*)(ws + off);   off += (((size_t)(NN + 1) * 4) + 255) & ~(size_t)255;
  int*   cursor   = (int*)(ws + off);   off += (((size_t)NN * 4) + 255) & ~(size_t)255;
  int*   csr      = (int*)(ws + off);   off += (size_t)NE * 4;
  float* agg      = (float*)(ws + off); off += (size_t)NN * 64 * 4;
  float* x_a      = (float*)(ws + off); off += (size_t)NN * 64 * 4;
  float* x_b      = (float*)(ws + off); off += (size_t)NN * 64 * 4;
  unsigned short* Wt  = (unsigned short*)(ws + off); off += (size_t)NL * 16384 * 2;
  unsigned short* efb = (unsigned short*)(ws + off); off += (size_t)NE * 64 * 2;
  unsigned short* xbm = (unsigned short*)(ws + off); off += (size_t)NN * 64 * 2;

  hipMemsetAsync(deg, 0, (size_t)NN * 4, stream);
  k_deg<<<(NE + 255) / 256, 256, 0, stream>>>(trg, deg);
  k_scan<<<1, 1024, 0, stream>>>(deg, rowstart, cursor);
  k_fill<<<(NE + 255) / 256, 256, 0, stream>>>(src, trg, cursor, csr);
  k_wprep<<<(NL * 16384) / 256, 256, 0, stream>>>(W_fc, Wt);

  const float* xcur = x_in;
  float* xnext = x_a;

  for (int i = 0; i < NL; i++) {
    int relu = (i > 0) ? 1 : 0;
    k_agg<<<(NN * 16) / 256, 256, 0, stream>>>(xcur, rowstart, csr, agg, relu);
    k_conv<<<NN / 4, 256, 0, stream>>>(xcur, agg,
                                       W_self + (size_t)i * 4096,
                                       W_nbr + (size_t)i * 4096,
                                       b_conv + (size_t)i * 64,
                                       xnext, xbm, relu);
    const unsigned short* Wti = Wt + (size_t)i * 16384;
    const float* w256 = W_fc + ((size_t)i * 257 + 256) * 64;
    const float* bfc = b_fc + (size_t)i * 64;
    if (i == 0) {
      k_edge<0, 1><<<NE / 128, 256, 0, stream>>>(xbm, src, trg, ef_in,
                                                 Wti, w256, bfc, efb);
    } else if (i == 1) {
      k_edge<1, 1><<<NE / 128, 256, 0, stream>>>(xbm, src, trg, efb,
                                                 Wti, w256, bfc, efb);
    } else {
      k_edge<1, 0><<<NE / 128, 256, 0, stream>>>(xbm, src, trg, efb,
                                                 Wti, w256, bfc, out);
    }
    xcur = xnext;
    xnext = (xnext == x_a) ? x_b : x_a;
  }
}

// Round 5
// 753.098 us; speedup vs baseline: 1.5579x; 1.0002x over previous
//
#include <hip/hip_runtime.h>

#define NN 50000
#define NE 800000
#define NL 3

typedef __bf16 bf16x8 __attribute__((ext_vector_type(8)));
typedef float f32x16 __attribute__((ext_vector_type(16)));
typedef unsigned int u32x4 __attribute__((ext_vector_type(4)));

// ---------------- zero degree array (hipMemsetAsync's fillBuffer ran at 117us!) ----------------
__global__ __launch_bounds__(256) void k_zero(float* __restrict__ deg) {
  int i = blockIdx.x * 256 + threadIdx.x;
  if (i < NN) deg[i] = 0.f;
}

// ---------------- degree histogram ----------------
__global__ __launch_bounds__(256) void k_deg(const int* __restrict__ trg,
                                             float* __restrict__ deg) {
  int e = blockIdx.x * 256 + threadIdx.x;
  if (e < NE) atomicAdd(&deg[trg[e]], 1.0f);
}

// ---------------- exclusive scan of degrees -> CSR row starts ----------------
__global__ __launch_bounds__(1024) void k_scan(const float* __restrict__ deg,
                                               int* __restrict__ rowstart,
                                               int* __restrict__ cursor) {
  __shared__ int part[1024];
  int t = threadIdx.x;
  int t0 = t * 49, t1 = min(t0 + 49, NN);
  int s = 0;
  for (int i = t0; i < t1; i++) s += (int)deg[i];
  part[t] = s;
  __syncthreads();
  for (int off = 1; off < 1024; off <<= 1) {
    int vv = (t >= off) ? part[t - off] : 0;
    int v = part[t];
    __syncthreads();
    part[t] = v + vv;
    __syncthreads();
  }
  int run = part[t] - s;  // exclusive prefix
  for (int i = t0; i < t1; i++) {
    rowstart[i] = run;
    cursor[i] = run;
    run += (int)deg[i];
  }
  if (t == 1023) rowstart[NN] = NE;
}

// ---------------- CSR fill: bucket src ids by trg ----------------
__global__ __launch_bounds__(256) void k_fill(const int* __restrict__ src,
                                              const int* __restrict__ trg,
                                              int* __restrict__ cursor,
                                              int* __restrict__ csr) {
  int e = blockIdx.x * 256 + threadIdx.x;
  if (e < NE) {
    int pos = atomicAdd(&cursor[trg[e]], 1);
    csr[pos] = src[e];
  }
}

// ---------------- gather aggregation (mean, deg-division folded) ----------------
__global__ __launch_bounds__(256) void k_agg(const float* __restrict__ x,
                                             const int* __restrict__ rowstart,
                                             const int* __restrict__ csr,
                                             float* __restrict__ agg, int relu) {
  int i = blockIdx.x * 256 + threadIdx.x;
  int n = i >> 4, q = i & 15;
  const float4* x4 = (const float4*)x;
  int b = rowstart[n], en = rowstart[n + 1];
  float4 v = make_float4(0.f, 0.f, 0.f, 0.f);
  for (int j = b; j < en; j++) {
    float4 a = x4[(size_t)csr[j] * 16 + q];
    if (relu) {
      a.x = fmaxf(a.x, 0.f); a.y = fmaxf(a.y, 0.f);
      a.z = fmaxf(a.z, 0.f); a.w = fmaxf(a.w, 0.f);
    }
    v.x += a.x; v.y += a.y; v.z += a.z; v.w += a.w;
  }
  float inv = 1.0f / fmaxf((float)(en - b), 1.0f);
  v.x *= inv; v.y *= inv; v.z *= inv; v.w *= inv;
  ((float4*)agg)[(size_t)n * 16 + q] = v;
}

// ---------------- node conv: xout = relu?(x)@Ws + agg@Wn + b (+ bf16 mirror) ----------------
__global__ __launch_bounds__(256) void k_conv(const float* __restrict__ x,
                                              const float* __restrict__ agg,
                                              const float* __restrict__ Ws,
                                              const float* __restrict__ Wn,
                                              const float* __restrict__ bc,
                                              float* __restrict__ xout,
                                              unsigned short* __restrict__ xb,
                                              int relu) {
  __shared__ float sWs[64 * 64];
  __shared__ float sWn[64 * 64];
  __shared__ float sx[4][64];
  __shared__ float sa[4][64];
  int tid = threadIdx.x;
  for (int i = tid; i < 4096; i += 256) { sWs[i] = Ws[i]; sWn[i] = Wn[i]; }
  int g = tid >> 6, lane = tid & 63;
  int n = blockIdx.x * 4 + g;
  float xv = x[(size_t)n * 64 + lane];
  if (relu) xv = fmaxf(xv, 0.f);
  sx[g][lane] = xv;
  sa[g][lane] = agg[(size_t)n * 64 + lane];
  __syncthreads();
  float acc = bc[lane];
  #pragma unroll
  for (int k = 0; k < 64; k++) {
    acc += sx[g][k] * sWs[k * 64 + lane] + sa[g][k] * sWn[k * 64 + lane];
  }
  xout[(size_t)n * 64 + lane] = acc;
  xb[(size_t)n * 64 + lane] = __builtin_bit_cast(unsigned short, (__bf16)acc);
}

// ---------------- W_fc prep into MFMA-B LDS layout ----------------
// Wt2[l][ks][kg][col][e] = bf16(W_fc[l][ks*16+kg*8+e][col]); 16*2*64*8 = 16K
// ushorts = 32KB per layer. k_edge block-copies this linearly into LDS; the
// B-frag ds_read for (ks,kg,col) is then a contiguous 1KB/wave access
// (conflict-free).
__global__ __launch_bounds__(256) void k_wprep(const float* __restrict__ Wfc,
                                               unsigned short* __restrict__ Wt) {
  int idx = blockIdx.x * 256 + threadIdx.x;   // [0, 3*16384)
  int l = idx >> 14;
  int o = idx & 16383;
  int e = o & 7;
  int col = (o >> 3) & 63;
  int kg = (o >> 9) & 1;
  int ks = o >> 10;
  int k = ks * 16 + kg * 8 + e;
  float v = Wfc[((size_t)l * 257 + k) * 64 + col];
  Wt[idx] = __builtin_bit_cast(unsigned short, (__bf16)v);
}

__device__ inline u32x4 pack8(const float* f) {
  u32x4 r;
  #pragma unroll
  for (int i = 0; i < 4; i++) {
    unsigned short lo = __builtin_bit_cast(unsigned short, (__bf16)f[2 * i]);
    unsigned short hi = __builtin_bit_cast(unsigned short, (__bf16)f[2 * i + 1]);
    r[i] = (unsigned)lo | ((unsigned)hi << 16);
  }
  return r;
}

__device__ inline float bflo(unsigned u) {
  return __builtin_bit_cast(float, u << 16);
}
__device__ inline float bfhi(unsigned u) {
  return __builtin_bit_cast(float, u & 0xffff0000u);
}

// ---------------- edge update v8: R2 structure + Wt in LDS ----------------
// Confirmed (R4): k_edge was L2-request bound; Wt's divergent 512B-strided
// B-frag reads were 25.6M requests/dispatch (~75%). Staging Wt in LDS
// (coalesced 32KB copy, one initial barrier) halved k_edge to 116us.
// Contiguous tile mapping, one tile per wave, no in-loop barriers.
template <int IN_BF16, int OUT_BF16>
__global__ __launch_bounds__(256, 4) void k_edge(
    const unsigned short* __restrict__ xb, const int* __restrict__ src,
    const int* __restrict__ trg, const void* ef_in,
    const unsigned short* __restrict__ Wt, const float* __restrict__ w256,
    const float* __restrict__ bfc, void* ef_out) {
  __shared__ __align__(16) unsigned short sB[16384];  // 32KB: [ks][kg][col][8]

  int t = threadIdx.x;
  // ---- stage Wt -> LDS (linear, coalesced, L2-hot) ----
  {
    const u32x4* wg = (const u32x4*)Wt;
    u32x4* sb = (u32x4*)sB;
    #pragma unroll
    for (int i = 0; i < 8; i++) sb[t + 256 * i] = wg[t + 256 * i];
  }
  __syncthreads();
  const u32x4* sb4 = (const u32x4*)sB;

  int w = t >> 6;
  int lane = t & 63;
  int rl = lane & 31;   // edge within tile == MFMA row == output col offset
  int kg = lane >> 5;   // k-half
  int e0 = (blockIdx.x * 4 + w) * 32;
  int e = e0 + rl;

  int se = src[e], te = trg[e];

  // ---- issue ef load first (streaming) ----
  u32x4 efr[4];
  if (IN_BF16) {
    const u32x4* eb = (const u32x4*)ef_in;
    #pragma unroll
    for (int j = 0; j < 4; j++) efr[j] = eb[(size_t)e * 8 + j * 2 + kg];
  } else {
    const float4* ef4 = (const float4*)ef_in;
    #pragma unroll
    for (int j = 0; j < 4; j++) {
      float4 a = ef4[(size_t)e * 16 + j * 4 + kg * 2];
      float4 b = ef4[(size_t)e * 16 + j * 4 + kg * 2 + 1];
      float f[8] = {a.x, a.y, a.z, a.w, b.x, b.y, b.z, b.w};
      efr[j] = pack8(f);
    }
  }

  // ---- issue x gathers (random bf16 128B rows) ----
  const u32x4* xq = (const u32x4*)xb;
  u32x4 sfr[4], tfr[4];
  #pragma unroll
  for (int j = 0; j < 4; j++) {
    sfr[j] = xq[(size_t)se * 8 + j * 2 + kg];
    tfr[j] = xq[(size_t)te * 8 + j * 2 + kg];
  }

  int col0 = rl, col1 = 32 + rl;
  float wv0 = w256[col0], wv1 = w256[col1];
  f32x16 acc0, acc1;
  {
    float b0 = bfc[col0], b1 = bfc[col1];
    #pragma unroll
    for (int r = 0; r < 16; r++) { acc0[r] = b0; acc1[r] = b1; }
  }

  // ---- ef MFMAs (k 0..63): overlap x-gather latency ----
  #pragma unroll
  for (int ks = 0; ks < 4; ks++) {
    bf16x8 av = __builtin_bit_cast(bf16x8, efr[ks]);
    int bi = (ks * 2 + kg) * 64;
    acc0 = __builtin_amdgcn_mfma_f32_32x32x16_bf16(
        av, __builtin_bit_cast(bf16x8, sb4[bi + col0]), acc0, 0, 0, 0);
    acc1 = __builtin_amdgcn_mfma_f32_32x32x16_bf16(
        av, __builtin_bit_cast(bf16x8, sb4[bi + col1]), acc1, 0, 0, 0);
  }
  // ---- xs MFMAs (k 64..127) ----
  #pragma unroll
  for (int ks = 4; ks < 8; ks++) {
    bf16x8 av = __builtin_bit_cast(bf16x8, sfr[ks - 4]);
    int bi = (ks * 2 + kg) * 64;
    acc0 = __builtin_amdgcn_mfma_f32_32x32x16_bf16(
        av, __builtin_bit_cast(bf16x8, sb4[bi + col0]), acc0, 0, 0, 0);
    acc1 = __builtin_amdgcn_mfma_f32_32x32x16_bf16(
        av, __builtin_bit_cast(bf16x8, sb4[bi + col1]), acc1, 0, 0, 0);
  }
  // ---- xt MFMAs (k 128..191) ----
  #pragma unroll
  for (int ks = 8; ks < 12; ks++) {
    bf16x8 av = __builtin_bit_cast(bf16x8, tfr[ks - 8]);
    int bi = (ks * 2 + kg) * 64;
    acc0 = __builtin_amdgcn_mfma_f32_32x32x16_bf16(
        av, __builtin_bit_cast(bf16x8, sb4[bi + col0]), acc0, 0, 0, 0);
    acc1 = __builtin_amdgcn_mfma_f32_32x32x16_bf16(
        av, __builtin_bit_cast(bf16x8, sb4[bi + col1]), acc1, 0, 0, 0);
  }

  // ---- sim partials + |xs-xt| frags (from bf16-rounded values) ----
  float dot = 0.f, n1 = 0.f, n2 = 0.f;
  u32x4 dfr[4];
  #pragma unroll
  for (int j = 0; j < 4; j++) {
    float fs[8], ft[8], fd[8];
    #pragma unroll
    for (int q = 0; q < 4; q++) {
      fs[2 * q] = bflo(sfr[j][q]); fs[2 * q + 1] = bfhi(sfr[j][q]);
      ft[2 * q] = bflo(tfr[j][q]); ft[2 * q + 1] = bfhi(tfr[j][q]);
    }
    #pragma unroll
    for (int c = 0; c < 8; c++) {
      dot = fmaf(fs[c], ft[c], dot);
      n1 = fmaf(fs[c], fs[c], n1);
      n2 = fmaf(ft[c], ft[c], n2);
      fd[c] = fabsf(fs[c] - ft[c]);
    }
    dfr[j] = pack8(fd);
  }

  // ---- |xs-xt| MFMAs (k 192..255) ----
  #pragma unroll
  for (int ks = 12; ks < 16; ks++) {
    bf16x8 av = __builtin_bit_cast(bf16x8, dfr[ks - 12]);
    int bi = (ks * 2 + kg) * 64;
    acc0 = __builtin_amdgcn_mfma_f32_32x32x16_bf16(
        av, __builtin_bit_cast(bf16x8, sb4[bi + col0]), acc0, 0, 0, 0);
    acc1 = __builtin_amdgcn_mfma_f32_32x32x16_bf16(
        av, __builtin_bit_cast(bf16x8, sb4[bi + col1]), acc1, 0, 0, 0);
  }

  // ---- combine kg-halves -> sim; fold sim-column (k=256) into output ----
  dot += __shfl_xor(dot, 32);
  n1 += __shfl_xor(n1, 32);
  n2 += __shfl_xor(n2, 32);
  float sim = dot / fmaxf(sqrtf(n1) * sqrtf(n2), 1e-8f);

  // ---- store C (bf16 inter-layer, fp32 final) ----
  #pragma unroll
  for (int r = 0; r < 16; r++) {
    int row = (r & 3) + 8 * (r >> 2) + 4 * kg;
    float s = __shfl(sim, row);
    float o0 = fmaf(s, wv0, acc0[r]);
    float o1 = fmaf(s, wv1, acc1[r]);
    size_t base = (size_t)(e0 + row) * 64;
    if (OUT_BF16) {
      unsigned short* ob = (unsigned short*)ef_out;
      ob[base + col0] = __builtin_bit_cast(unsigned short, (__bf16)o0);
      ob[base + col1] = __builtin_bit_cast(unsigned short, (__bf16)o1);
    } else {
      float* of = (float*)ef_out;
      of[base + col0] = o0;
      of[base + col1] = o1;
    }
  }
}

extern "C" void kernel_launch(void* const* d_in, const int* in_sizes, int n_in,
                              void* d_out, int out_size, void* d_ws, size_t ws_size,
                              hipStream_t stream) {
  const float* x_in   = (const float*)d_in[0];
  const int*   ei     = (const int*)d_in[1];
  const float* ef_in  = (const float*)d_in[2];
  const float* W_self = (const float*)d_in[3];
  const float* W_nbr  = (const float*)d_in[4];
  const float* b_conv = (const float*)d_in[5];
  const float* W_fc   = (const float*)d_in[6];
  const float* b_fc   = (const float*)d_in[7];
  float* out = (float*)d_out;

  const int* src = ei;
  const int* trg = ei + NE;

  char* ws = (char*)d_ws;
  size_t off = 0;
  float* deg      = (float*)(ws + off); off += (((size_t)NN * 4) + 255) & ~(size_t)255;
  int*   rowstart = (int*)(ws + off);   off += (((size_t)(NN + 1) * 4) + 255) & ~(size_t)255;
  int*   cursor   = (int*)(ws + off);   off += (((size_t)NN * 4) + 255) & ~(size_t)255;
  int*   csr      = (int*)(ws + off);   off += (size_t)NE * 4;
  float* agg      = (float*)(ws + off); off += (size_t)NN * 64 * 4;
  float* x_a      = (float*)(ws + off); off += (size_t)NN * 64 * 4;
  float* x_b      = (float*)(ws + off); off += (size_t)NN * 64 * 4;
  unsigned short* Wt  = (unsigned short*)(ws + off); off += (size_t)NL * 16384 * 2;
  unsigned short* efb = (unsigned short*)(ws + off); off += (size_t)NE * 64 * 2;
  unsigned short* xbm = (unsigned short*)(ws + off); off += (size_t)NN * 64 * 2;

  k_zero<<<(NN + 255) / 256, 256, 0, stream>>>(deg);
  k_deg<<<(NE + 255) / 256, 256, 0, stream>>>(trg, deg);
  k_scan<<<1, 1024, 0, stream>>>(deg, rowstart, cursor);
  k_fill<<<(NE + 255) / 256, 256, 0, stream>>>(src, trg, cursor, csr);
  k_wprep<<<(NL * 16384) / 256, 256, 0, stream>>>(W_fc, Wt);

  const float* xcur = x_in;
  float* xnext = x_a;

  for (int i = 0; i < NL; i++) {
    int relu = (i > 0) ? 1 : 0;
    k_agg<<<(NN * 16) / 256, 256, 0, stream>>>(xcur, rowstart, csr, agg, relu);
    k_conv<<<NN / 4, 256, 0, stream>>>(xcur, agg,
                                       W_self + (size_t)i * 4096,
                                       W_nbr + (size_t)i * 4096,
                                       b_conv + (size_t)i * 64,
                                       xnext, xbm, relu);
    const unsigned short* Wti = Wt + (size_t)i * 16384;
    const float* w256 = W_fc + ((size_t)i * 257 + 256) * 64;
    const float* bfc = b_fc + (size_t)i * 64;
    if (i == 0) {
      k_edge<0, 1><<<NE / 128, 256, 0, stream>>>(xbm, src, trg, ef_in,
                                                 Wti, w256, bfc, efb);
    } else if (i == 1) {
      k_edge<1, 1><<<NE / 128, 256, 0, stream>>>(xbm, src, trg, efb,
                                                 Wti, w256, bfc, efb);
    } else {
      k_edge<1, 0><<<NE / 128, 256, 0, stream>>>(xbm, src, trg, efb,
                                                 Wti, w256, bfc, out);
    }
    xcur = xnext;
    xnext = (xnext == x_a) ? x_b : x_a;
  }
}

// Round 6
// 723.161 us; speedup vs baseline: 1.6224x; 1.0414x over previous
//
#include <hip/hip_runtime.h>

#define NN 50000
#define NE 800000
#define NL 3

typedef __bf16 bf16x8 __attribute__((ext_vector_type(8)));
typedef float f32x16 __attribute__((ext_vector_type(16)));
typedef unsigned int u32x4 __attribute__((ext_vector_type(4)));

// ---------------- zero degree array ----------------
__global__ __launch_bounds__(256) void k_zero(float* __restrict__ deg) {
  int i = blockIdx.x * 256 + threadIdx.x;
  if (i < NN) deg[i] = 0.f;
}

// ---------------- degree histogram ----------------
__global__ __launch_bounds__(256) void k_deg(const int* __restrict__ trg,
                                             float* __restrict__ deg) {
  int e = blockIdx.x * 256 + threadIdx.x;
  if (e < NE) atomicAdd(&deg[trg[e]], 1.0f);
}

// ---------------- exclusive scan of degrees -> CSR row starts ----------------
__global__ __launch_bounds__(1024) void k_scan(const float* __restrict__ deg,
                                               int* __restrict__ rowstart,
                                               int* __restrict__ cursor) {
  __shared__ int part[1024];
  int t = threadIdx.x;
  int t0 = t * 49, t1 = min(t0 + 49, NN);
  int s = 0;
  for (int i = t0; i < t1; i++) s += (int)deg[i];
  part[t] = s;
  __syncthreads();
  for (int off = 1; off < 1024; off <<= 1) {
    int vv = (t >= off) ? part[t - off] : 0;
    int v = part[t];
    __syncthreads();
    part[t] = v + vv;
    __syncthreads();
  }
  int run = part[t] - s;  // exclusive prefix
  for (int i = t0; i < t1; i++) {
    rowstart[i] = run;
    cursor[i] = run;
    run += (int)deg[i];
  }
  if (t == 1023) rowstart[NN] = NE;
}

// ---------------- CSR fill: bucket src ids by trg ----------------
__global__ __launch_bounds__(256) void k_fill(const int* __restrict__ src,
                                              const int* __restrict__ trg,
                                              int* __restrict__ cursor,
                                              int* __restrict__ csr) {
  int e = blockIdx.x * 256 + threadIdx.x;
  if (e < NE) {
    int pos = atomicAdd(&cursor[trg[e]], 1);
    csr[pos] = src[e];
  }
}

__device__ inline u32x4 pack8(const float* f) {
  u32x4 r;
  #pragma unroll
  for (int i = 0; i < 4; i++) {
    unsigned short lo = __builtin_bit_cast(unsigned short, (__bf16)f[2 * i]);
    unsigned short hi = __builtin_bit_cast(unsigned short, (__bf16)f[2 * i + 1]);
    r[i] = (unsigned)lo | ((unsigned)hi << 16);
  }
  return r;
}

__device__ inline float bflo(unsigned u) {
  return __builtin_bit_cast(float, u << 16);
}
__device__ inline float bfhi(unsigned u) {
  return __builtin_bit_cast(float, u & 0xffff0000u);
}

// ---------------- bf16 mirror of x_in (layer-0 gather source) ----------------
__global__ __launch_bounds__(256) void k_xmir(const float* __restrict__ x,
                                              unsigned short* __restrict__ xb) {
  int i = blockIdx.x * 256 + threadIdx.x;   // NN*8 items, 8 elems each
  if (i < NN * 8) {
    const float4* x4 = (const float4*)x;
    float4 a = x4[2 * i], b = x4[2 * i + 1];
    float f[8] = {a.x, a.y, a.z, a.w, b.x, b.y, b.z, b.w};
    ((u32x4*)xb)[i] = pack8(f);
  }
}

// ---------------- gather aggregation v2: bf16 rows (half bytes, half requests) ----------------
// R4 proved the gather kernels are L2-request bound. Gather from the bf16
// mirror (128B rows, 2 segments/row instead of 4): 3.2M -> 1.6M segment
// requests per layer. 8 lanes/node x 16B chunk; unpack+accumulate fp32.
// relu commutes with bf16 rounding (monotone).
__global__ __launch_bounds__(256) void k_agg(const unsigned short* __restrict__ xb,
                                             const int* __restrict__ rowstart,
                                             const int* __restrict__ csr,
                                             float* __restrict__ agg, int relu) {
  int i = blockIdx.x * 256 + threadIdx.x;
  if (i >= NN * 8) return;
  int n = i >> 3, q = i & 7;                 // chunk q: bf16 cols [8q, 8q+8)
  const u32x4* xq = (const u32x4*)xb;
  int b = rowstart[n], en = rowstart[n + 1];
  float acc[8] = {0.f, 0.f, 0.f, 0.f, 0.f, 0.f, 0.f, 0.f};
  for (int j = b; j < en; j++) {
    u32x4 v = xq[(size_t)csr[j] * 8 + q];
    #pragma unroll
    for (int c = 0; c < 4; c++) {
      float lo = bflo(v[c]), hi = bfhi(v[c]);
      if (relu) { lo = fmaxf(lo, 0.f); hi = fmaxf(hi, 0.f); }
      acc[2 * c] += lo;
      acc[2 * c + 1] += hi;
    }
  }
  float inv = 1.0f / fmaxf((float)(en - b), 1.0f);
  float4 o0 = {acc[0] * inv, acc[1] * inv, acc[2] * inv, acc[3] * inv};
  float4 o1 = {acc[4] * inv, acc[5] * inv, acc[6] * inv, acc[7] * inv};
  float4* a4 = (float4*)agg;
  a4[(size_t)n * 16 + q * 2] = o0;
  a4[(size_t)n * 16 + q * 2 + 1] = o1;
}

// ---------------- node conv: xout = relu?(x)@Ws + agg@Wn + b (+ bf16 mirror) ----------------
__global__ __launch_bounds__(256) void k_conv(const float* __restrict__ x,
                                              const float* __restrict__ agg,
                                              const float* __restrict__ Ws,
                                              const float* __restrict__ Wn,
                                              const float* __restrict__ bc,
                                              float* __restrict__ xout,
                                              unsigned short* __restrict__ xb,
                                              int relu) {
  __shared__ float sWs[64 * 64];
  __shared__ float sWn[64 * 64];
  __shared__ float sx[4][64];
  __shared__ float sa[4][64];
  int tid = threadIdx.x;
  for (int i = tid; i < 4096; i += 256) { sWs[i] = Ws[i]; sWn[i] = Wn[i]; }
  int g = tid >> 6, lane = tid & 63;
  int n = blockIdx.x * 4 + g;
  float xv = x[(size_t)n * 64 + lane];
  if (relu) xv = fmaxf(xv, 0.f);
  sx[g][lane] = xv;
  sa[g][lane] = agg[(size_t)n * 64 + lane];
  __syncthreads();
  float acc = bc[lane];
  #pragma unroll
  for (int k = 0; k < 64; k++) {
    acc += sx[g][k] * sWs[k * 64 + lane] + sa[g][k] * sWn[k * 64 + lane];
  }
  xout[(size_t)n * 64 + lane] = acc;
  xb[(size_t)n * 64 + lane] = __builtin_bit_cast(unsigned short, (__bf16)acc);
}

// ---------------- W_fc prep into MFMA-B LDS layout ----------------
// Wt2[l][ks][kg][col][e] = bf16(W_fc[l][ks*16+kg*8+e][col]); 32KB per layer.
__global__ __launch_bounds__(256) void k_wprep(const float* __restrict__ Wfc,
                                               unsigned short* __restrict__ Wt) {
  int idx = blockIdx.x * 256 + threadIdx.x;   // [0, 3*16384)
  int l = idx >> 14;
  int o = idx & 16383;
  int e = o & 7;
  int col = (o >> 3) & 63;
  int kg = (o >> 9) & 1;
  int ks = o >> 10;
  int k = ks * 16 + kg * 8 + e;
  float v = Wfc[((size_t)l * 257 + k) * 64 + col];
  Wt[idx] = __builtin_bit_cast(unsigned short, (__bf16)v);
}

// ---------------- edge update v8: Wt in LDS (confirmed R4: -110us) ----------------
template <int IN_BF16, int OUT_BF16>
__global__ __launch_bounds__(256, 4) void k_edge(
    const unsigned short* __restrict__ xb, const int* __restrict__ src,
    const int* __restrict__ trg, const void* ef_in,
    const unsigned short* __restrict__ Wt, const float* __restrict__ w256,
    const float* __restrict__ bfc, void* ef_out) {
  __shared__ __align__(16) unsigned short sB[16384];  // 32KB: [ks][kg][col][8]

  int t = threadIdx.x;
  // ---- stage Wt -> LDS (linear, coalesced, L2-hot) ----
  {
    const u32x4* wg = (const u32x4*)Wt;
    u32x4* sb = (u32x4*)sB;
    #pragma unroll
    for (int i = 0; i < 8; i++) sb[t + 256 * i] = wg[t + 256 * i];
  }
  __syncthreads();
  const u32x4* sb4 = (const u32x4*)sB;

  int w = t >> 6;
  int lane = t & 63;
  int rl = lane & 31;   // edge within tile == MFMA row == output col offset
  int kg = lane >> 5;   // k-half
  int e0 = (blockIdx.x * 4 + w) * 32;
  int e = e0 + rl;

  int se = src[e], te = trg[e];

  // ---- issue ef load first (streaming) ----
  u32x4 efr[4];
  if (IN_BF16) {
    const u32x4* eb = (const u32x4*)ef_in;
    #pragma unroll
    for (int j = 0; j < 4; j++) efr[j] = eb[(size_t)e * 8 + j * 2 + kg];
  } else {
    const float4* ef4 = (const float4*)ef_in;
    #pragma unroll
    for (int j = 0; j < 4; j++) {
      float4 a = ef4[(size_t)e * 16 + j * 4 + kg * 2];
      float4 b = ef4[(size_t)e * 16 + j * 4 + kg * 2 + 1];
      float f[8] = {a.x, a.y, a.z, a.w, b.x, b.y, b.z, b.w};
      efr[j] = pack8(f);
    }
  }

  // ---- issue x gathers (random bf16 128B rows) ----
  const u32x4* xq = (const u32x4*)xb;
  u32x4 sfr[4], tfr[4];
  #pragma unroll
  for (int j = 0; j < 4; j++) {
    sfr[j] = xq[(size_t)se * 8 + j * 2 + kg];
    tfr[j] = xq[(size_t)te * 8 + j * 2 + kg];
  }

  int col0 = rl, col1 = 32 + rl;
  float wv0 = w256[col0], wv1 = w256[col1];
  f32x16 acc0, acc1;
  {
    float b0 = bfc[col0], b1 = bfc[col1];
    #pragma unroll
    for (int r = 0; r < 16; r++) { acc0[r] = b0; acc1[r] = b1; }
  }

  // ---- ef MFMAs (k 0..63): overlap x-gather latency ----
  #pragma unroll
  for (int ks = 0; ks < 4; ks++) {
    bf16x8 av = __builtin_bit_cast(bf16x8, efr[ks]);
    int bi = (ks * 2 + kg) * 64;
    acc0 = __builtin_amdgcn_mfma_f32_32x32x16_bf16(
        av, __builtin_bit_cast(bf16x8, sb4[bi + col0]), acc0, 0, 0, 0);
    acc1 = __builtin_amdgcn_mfma_f32_32x32x16_bf16(
        av, __builtin_bit_cast(bf16x8, sb4[bi + col1]), acc1, 0, 0, 0);
  }
  // ---- xs MFMAs (k 64..127) ----
  #pragma unroll
  for (int ks = 4; ks < 8; ks++) {
    bf16x8 av = __builtin_bit_cast(bf16x8, sfr[ks - 4]);
    int bi = (ks * 2 + kg) * 64;
    acc0 = __builtin_amdgcn_mfma_f32_32x32x16_bf16(
        av, __builtin_bit_cast(bf16x8, sb4[bi + col0]), acc0, 0, 0, 0);
    acc1 = __builtin_amdgcn_mfma_f32_32x32x16_bf16(
        av, __builtin_bit_cast(bf16x8, sb4[bi + col1]), acc1, 0, 0, 0);
  }
  // ---- xt MFMAs (k 128..191) ----
  #pragma unroll
  for (int ks = 8; ks < 12; ks++) {
    bf16x8 av = __builtin_bit_cast(bf16x8, tfr[ks - 8]);
    int bi = (ks * 2 + kg) * 64;
    acc0 = __builtin_amdgcn_mfma_f32_32x32x16_bf16(
        av, __builtin_bit_cast(bf16x8, sb4[bi + col0]), acc0, 0, 0, 0);
    acc1 = __builtin_amdgcn_mfma_f32_32x32x16_bf16(
        av, __builtin_bit_cast(bf16x8, sb4[bi + col1]), acc1, 0, 0, 0);
  }

  // ---- sim partials + |xs-xt| frags (from bf16-rounded values) ----
  float dot = 0.f, n1 = 0.f, n2 = 0.f;
  u32x4 dfr[4];
  #pragma unroll
  for (int j = 0; j < 4; j++) {
    float fs[8], ft[8], fd[8];
    #pragma unroll
    for (int q = 0; q < 4; q++) {
      fs[2 * q] = bflo(sfr[j][q]); fs[2 * q + 1] = bfhi(sfr[j][q]);
      ft[2 * q] = bflo(tfr[j][q]); ft[2 * q + 1] = bfhi(tfr[j][q]);
    }
    #pragma unroll
    for (int c = 0; c < 8; c++) {
      dot = fmaf(fs[c], ft[c], dot);
      n1 = fmaf(fs[c], fs[c], n1);
      n2 = fmaf(ft[c], ft[c], n2);
      fd[c] = fabsf(fs[c] - ft[c]);
    }
    dfr[j] = pack8(fd);
  }

  // ---- |xs-xt| MFMAs (k 192..255) ----
  #pragma unroll
  for (int ks = 12; ks < 16; ks++) {
    bf16x8 av = __builtin_bit_cast(bf16x8, dfr[ks - 12]);
    int bi = (ks * 2 + kg) * 64;
    acc0 = __builtin_amdgcn_mfma_f32_32x32x16_bf16(
        av, __builtin_bit_cast(bf16x8, sb4[bi + col0]), acc0, 0, 0, 0);
    acc1 = __builtin_amdgcn_mfma_f32_32x32x16_bf16(
        av, __builtin_bit_cast(bf16x8, sb4[bi + col1]), acc1, 0, 0, 0);
  }

  // ---- combine kg-halves -> sim; fold sim-column (k=256) into output ----
  dot += __shfl_xor(dot, 32);
  n1 += __shfl_xor(n1, 32);
  n2 += __shfl_xor(n2, 32);
  float sim = dot / fmaxf(sqrtf(n1) * sqrtf(n2), 1e-8f);

  // ---- store C (bf16 inter-layer, fp32 final) ----
  #pragma unroll
  for (int r = 0; r < 16; r++) {
    int row = (r & 3) + 8 * (r >> 2) + 4 * kg;
    float s = __shfl(sim, row);
    float o0 = fmaf(s, wv0, acc0[r]);
    float o1 = fmaf(s, wv1, acc1[r]);
    size_t base = (size_t)(e0 + row) * 64;
    if (OUT_BF16) {
      unsigned short* ob = (unsigned short*)ef_out;
      ob[base + col0] = __builtin_bit_cast(unsigned short, (__bf16)o0);
      ob[base + col1] = __builtin_bit_cast(unsigned short, (__bf16)o1);
    } else {
      float* of = (float*)ef_out;
      of[base + col0] = o0;
      of[base + col1] = o1;
    }
  }
}

extern "C" void kernel_launch(void* const* d_in, const int* in_sizes, int n_in,
                              void* d_out, int out_size, void* d_ws, size_t ws_size,
                              hipStream_t stream) {
  const float* x_in   = (const float*)d_in[0];
  const int*   ei     = (const int*)d_in[1];
  const float* ef_in  = (const float*)d_in[2];
  const float* W_self = (const float*)d_in[3];
  const float* W_nbr  = (const float*)d_in[4];
  const float* b_conv = (const float*)d_in[5];
  const float* W_fc   = (const float*)d_in[6];
  const float* b_fc   = (const float*)d_in[7];
  float* out = (float*)d_out;

  const int* src = ei;
  const int* trg = ei + NE;

  char* ws = (char*)d_ws;
  size_t off = 0;
  float* deg      = (float*)(ws + off); off += (((size_t)NN * 4) + 255) & ~(size_t)255;
  int*   rowstart = (int*)(ws + off);   off += (((size_t)(NN + 1) * 4) + 255) & ~(size_t)255;
  int*   cursor   = (int*)(ws + off);   off += (((size_t)NN * 4) + 255) & ~(size_t)255;
  int*   csr      = (int*)(ws + off);   off += (size_t)NE * 4;
  float* agg      = (float*)(ws + off); off += (size_t)NN * 64 * 4;
  float* x_a      = (float*)(ws + off); off += (size_t)NN * 64 * 4;
  float* x_b      = (float*)(ws + off); off += (size_t)NN * 64 * 4;
  unsigned short* Wt  = (unsigned short*)(ws + off); off += (size_t)NL * 16384 * 2;
  unsigned short* efb = (unsigned short*)(ws + off); off += (size_t)NE * 64 * 2;
  unsigned short* xbm = (unsigned short*)(ws + off); off += (size_t)NN * 64 * 2;

  k_zero<<<(NN + 255) / 256, 256, 0, stream>>>(deg);
  k_deg<<<(NE + 255) / 256, 256, 0, stream>>>(trg, deg);
  k_scan<<<1, 1024, 0, stream>>>(deg, rowstart, cursor);
  k_fill<<<(NE + 255) / 256, 256, 0, stream>>>(src, trg, cursor, csr);
  k_wprep<<<(NL * 16384) / 256, 256, 0, stream>>>(W_fc, Wt);
  k_xmir<<<(NN * 8 + 255) / 256, 256, 0, stream>>>(x_in, xbm);

  const float* xcur = x_in;
  float* xnext = x_a;

  for (int i = 0; i < NL; i++) {
    int relu = (i > 0) ? 1 : 0;
    // k_agg gathers from the bf16 mirror (layer 0: mirror of x_in; layers
    // 1,2: xbm written by previous k_conv). relu folded into unpack.
    k_agg<<<(NN * 8 + 255) / 256, 256, 0, stream>>>(xbm, rowstart, csr, agg, relu);
    k_conv<<<NN / 4, 256, 0, stream>>>(xcur, agg,
                                       W_self + (size_t)i * 4096,
                                       W_nbr + (size_t)i * 4096,
                                       b_conv + (size_t)i * 64,
                                       xnext, xbm, relu);
    const unsigned short* Wti = Wt + (size_t)i * 16384;
    const float* w256 = W_fc + ((size_t)i * 257 + 256) * 64;
    const float* bfc = b_fc + (size_t)i * 64;
    if (i == 0) {
      k_edge<0, 1><<<NE / 128, 256, 0, stream>>>(xbm, src, trg, ef_in,
                                                 Wti, w256, bfc, efb);
    } else if (i == 1) {
      k_edge<1, 1><<<NE / 128, 256, 0, stream>>>(xbm, src, trg, efb,
                                                 Wti, w256, bfc, efb);
    } else {
      k_edge<1, 0><<<NE / 128, 256, 0, stream>>>(xbm, src, trg, efb,
                                                 Wti, w256, bfc, out);
    }
    xcur = xnext;
    xnext = (xnext == x_a) ? x_b : x_a;
  }
}

// Round 7
// 710.443 us; speedup vs baseline: 1.6514x; 1.0179x over previous
//
#include <hip/hip_runtime.h>

#define NN 50000
#define NE 800000
#define NL 3

typedef __bf16 bf16x8 __attribute__((ext_vector_type(8)));
typedef float f32x16 __attribute__((ext_vector_type(16)));
typedef unsigned int u32x4 __attribute__((ext_vector_type(4)));

// ---------------- zero degree array ----------------
__global__ __launch_bounds__(256) void k_zero(float* __restrict__ deg) {
  int i = blockIdx.x * 256 + threadIdx.x;
  if (i < NN) deg[i] = 0.f;
}

// ---------------- degree histogram ----------------
__global__ __launch_bounds__(256) void k_deg(const int* __restrict__ trg,
                                             float* __restrict__ deg) {
  int e = blockIdx.x * 256 + threadIdx.x;
  if (e < NE) atomicAdd(&deg[trg[e]], 1.0f);
}

// ---------------- exclusive scan of degrees -> CSR row starts ----------------
__global__ __launch_bounds__(1024) void k_scan(const float* __restrict__ deg,
                                               int* __restrict__ rowstart,
                                               int* __restrict__ cursor) {
  __shared__ int part[1024];
  int t = threadIdx.x;
  int t0 = t * 49, t1 = min(t0 + 49, NN);
  int s = 0;
  for (int i = t0; i < t1; i++) s += (int)deg[i];
  part[t] = s;
  __syncthreads();
  for (int off = 1; off < 1024; off <<= 1) {
    int vv = (t >= off) ? part[t - off] : 0;
    int v = part[t];
    __syncthreads();
    part[t] = v + vv;
    __syncthreads();
  }
  int run = part[t] - s;  // exclusive prefix
  for (int i = t0; i < t1; i++) {
    rowstart[i] = run;
    cursor[i] = run;
    run += (int)deg[i];
  }
  if (t == 1023) rowstart[NN] = NE;
}

// ---------------- CSR fill: bucket src ids by trg ----------------
__global__ __launch_bounds__(256) void k_fill(const int* __restrict__ src,
                                              const int* __restrict__ trg,
                                              int* __restrict__ cursor,
                                              int* __restrict__ csr) {
  int e = blockIdx.x * 256 + threadIdx.x;
  if (e < NE) {
    int pos = atomicAdd(&cursor[trg[e]], 1);
    csr[pos] = src[e];
  }
}

__device__ inline u32x4 pack8(const float* f) {
  u32x4 r;
  #pragma unroll
  for (int i = 0; i < 4; i++) {
    unsigned short lo = __builtin_bit_cast(unsigned short, (__bf16)f[2 * i]);
    unsigned short hi = __builtin_bit_cast(unsigned short, (__bf16)f[2 * i + 1]);
    r[i] = (unsigned)lo | ((unsigned)hi << 16);
  }
  return r;
}

__device__ inline float bflo(unsigned u) {
  return __builtin_bit_cast(float, u << 16);
}
__device__ inline float bfhi(unsigned u) {
  return __builtin_bit_cast(float, u & 0xffff0000u);
}

// ---------------- bf16 mirror of x_in (layer-0 gather source) ----------------
__global__ __launch_bounds__(256) void k_xmir(const float* __restrict__ x,
                                              unsigned short* __restrict__ xb) {
  int i = blockIdx.x * 256 + threadIdx.x;   // NN*8 items, 8 elems each
  if (i < NN * 8) {
    const float4* x4 = (const float4*)x;
    float4 a = x4[2 * i], b = x4[2 * i + 1];
    float f[8] = {a.x, a.y, a.z, a.w, b.x, b.y, b.z, b.w};
    ((u32x4*)xb)[i] = pack8(f);
  }
}

// ---------------- gather aggregation v3: depth-2 x-prefetch ----------------
// The csr[j] -> addr -> x-row chain was serial (~600cy/neighbor exposed).
// Explicit v0/v1 rotation keeps 2 x-rows in flight; csr lookahead folded in.
__global__ __launch_bounds__(256) void k_agg(const unsigned short* __restrict__ xb,
                                             const int* __restrict__ rowstart,
                                             const int* __restrict__ csr,
                                             float* __restrict__ agg, int relu) {
  int i = blockIdx.x * 256 + threadIdx.x;
  if (i >= NN * 8) return;
  int n = i >> 3, q = i & 7;                 // chunk q: bf16 cols [8q, 8q+8)
  const u32x4* xq = (const u32x4*)xb;
  int b = rowstart[n], en = rowstart[n + 1];
  int nj = en - b;
  float acc[8] = {0.f, 0.f, 0.f, 0.f, 0.f, 0.f, 0.f, 0.f};
  u32x4 v0 = {}, v1 = {};
  if (nj > 0) v0 = xq[(size_t)csr[b] * 8 + q];
  if (nj > 1) v1 = xq[(size_t)csr[b + 1] * 8 + q];
  for (int j = 0; j < nj; j++) {
    u32x4 v = v0;
    v0 = v1;
    if (j + 2 < nj) v1 = xq[(size_t)csr[b + j + 2] * 8 + q];
    #pragma unroll
    for (int c = 0; c < 4; c++) {
      float lo = bflo(v[c]), hi = bfhi(v[c]);
      if (relu) { lo = fmaxf(lo, 0.f); hi = fmaxf(hi, 0.f); }
      acc[2 * c] += lo;
      acc[2 * c + 1] += hi;
    }
  }
  float inv = 1.0f / fmaxf((float)nj, 1.0f);
  float4 o0 = {acc[0] * inv, acc[1] * inv, acc[2] * inv, acc[3] * inv};
  float4 o1 = {acc[4] * inv, acc[5] * inv, acc[6] * inv, acc[7] * inv};
  float4* a4 = (float4*)agg;
  a4[(size_t)n * 16 + q * 2] = o0;
  a4[(size_t)n * 16 + q * 2 + 1] = o1;
}

// ---------------- node conv: xout = relu?(x)@Ws + agg@Wn + b (+ bf16 mirror) ----------------
__global__ __launch_bounds__(256) void k_conv(const float* __restrict__ x,
                                              const float* __restrict__ agg,
                                              const float* __restrict__ Ws,
                                              const float* __restrict__ Wn,
                                              const float* __restrict__ bc,
                                              float* __restrict__ xout,
                                              unsigned short* __restrict__ xb,
                                              int relu) {
  __shared__ float sWs[64 * 64];
  __shared__ float sWn[64 * 64];
  __shared__ float sx[4][64];
  __shared__ float sa[4][64];
  int tid = threadIdx.x;
  for (int i = tid; i < 4096; i += 256) { sWs[i] = Ws[i]; sWn[i] = Wn[i]; }
  int g = tid >> 6, lane = tid & 63;
  int n = blockIdx.x * 4 + g;
  float xv = x[(size_t)n * 64 + lane];
  if (relu) xv = fmaxf(xv, 0.f);
  sx[g][lane] = xv;
  sa[g][lane] = agg[(size_t)n * 64 + lane];
  __syncthreads();
  float acc = bc[lane];
  #pragma unroll
  for (int k = 0; k < 64; k++) {
    acc += sx[g][k] * sWs[k * 64 + lane] + sa[g][k] * sWn[k * 64 + lane];
  }
  xout[(size_t)n * 64 + lane] = acc;
  xb[(size_t)n * 64 + lane] = __builtin_bit_cast(unsigned short, (__bf16)acc);
}

// ---------------- W_fc prep into MFMA-B LDS layout ----------------
// Wt2[l][ks][kg][col][e] = bf16(W_fc[l][ks*16+kg*8+e][col]); 32KB per layer.
__global__ __launch_bounds__(256) void k_wprep(const float* __restrict__ Wfc,
                                               unsigned short* __restrict__ Wt) {
  int idx = blockIdx.x * 256 + threadIdx.x;   // [0, 3*16384)
  int l = idx >> 14;
  int o = idx & 16383;
  int e = o & 7;
  int col = (o >> 3) & 63;
  int kg = (o >> 9) & 1;
  int ks = o >> 10;
  int k = ks * 16 + kg * 8 + e;
  float v = Wfc[((size_t)l * 257 + k) * 64 + col];
  Wt[idx] = __builtin_bit_cast(unsigned short, (__bf16)v);
}

// ---------------- edge update v9: 5 tiles/wave, depth-1 software pipeline ----------------
// R4 proved Wt->LDS removes the request bottleneck; counters then showed no
// saturated pipe (MfmaUtil 9, VALU 23, BW 30%, occ 37) -> latency-bound,
// one tile per wave = one exposed gather round-trip per tile. Now each wave
// owns 5 CONSECUTIVE tiles (locality preserved; R3's scatter mistake avoided)
// and prefetches tile k+1's ef/x loads before computing tile k. Parity
// register slots, fully unrolled (static indices). Wt staging amortized 5x.
#define NT_EDGE 5

template <int IN_BF16, int OUT_BF16>
__global__ __launch_bounds__(256, 2) void k_edge(
    const unsigned short* __restrict__ xb, const int* __restrict__ src,
    const int* __restrict__ trg, const void* ef_in,
    const unsigned short* __restrict__ Wt, const float* __restrict__ w256,
    const float* __restrict__ bfc, void* ef_out) {
  __shared__ __align__(16) unsigned short sB[16384];  // 32KB: [ks][kg][col][8]

  int t = threadIdx.x;
  {
    const u32x4* wg = (const u32x4*)Wt;
    u32x4* sb = (u32x4*)sB;
    #pragma unroll
    for (int i = 0; i < 8; i++) sb[t + 256 * i] = wg[t + 256 * i];
  }
  __syncthreads();
  const u32x4* sb4 = (const u32x4*)sB;

  int w = t >> 6;
  int lane = t & 63;
  int rl = lane & 31;
  int kg = lane >> 5;
  int base_tile = (blockIdx.x * 4 + w) * NT_EDGE;

  int col0 = rl, col1 = 32 + rl;
  float wv0 = w256[col0], wv1 = w256[col1];
  float b0 = bfc[col0], b1 = bfc[col1];

  const u32x4* xq = (const u32x4*)xb;
  const u32x4* eb = (const u32x4*)ef_in;
  const float4* ef4 = (const float4*)ef_in;

  u32x4 efr[2][4];     // bf16 ef slots (IN_BF16)
  float4 efraw[2][8];  // fp32 ef slots (!IN_BF16; packed at use)
  u32x4 sfr[2][4], tfr[2][4];

// ---- issue all loads for tile K into slot P ----
#define LOADT(K, P)                                                          \
  {                                                                          \
    int e_ = (base_tile + (K)) * 32 + rl;                                    \
    int se_ = src[e_], te_ = trg[e_];                                        \
    if (IN_BF16) {                                                           \
      _Pragma("unroll")                                                      \
      for (int j = 0; j < 4; j++) efr[P][j] = eb[(size_t)e_ * 8 + j * 2 + kg]; \
    } else {                                                                 \
      _Pragma("unroll")                                                      \
      for (int j = 0; j < 4; j++) {                                          \
        efraw[P][2 * j]     = ef4[(size_t)e_ * 16 + j * 4 + kg * 2];         \
        efraw[P][2 * j + 1] = ef4[(size_t)e_ * 16 + j * 4 + kg * 2 + 1];     \
      }                                                                      \
    }                                                                        \
    _Pragma("unroll")                                                        \
    for (int j = 0; j < 4; j++) {                                            \
      sfr[P][j] = xq[(size_t)se_ * 8 + j * 2 + kg];                          \
      tfr[P][j] = xq[(size_t)te_ * 8 + j * 2 + kg];                          \
    }                                                                        \
  }

// ---- full compute + store for tile K from slot P ----
#define COMPT(K, P)                                                          \
  {                                                                          \
    int e0_ = (base_tile + (K)) * 32;                                        \
    u32x4 efp[4];                                                            \
    if (IN_BF16) {                                                           \
      _Pragma("unroll")                                                      \
      for (int j = 0; j < 4; j++) efp[j] = efr[P][j];                        \
    } else {                                                                 \
      _Pragma("unroll")                                                      \
      for (int j = 0; j < 4; j++) {                                          \
        float f_[8] = {efraw[P][2 * j].x, efraw[P][2 * j].y,                 \
                       efraw[P][2 * j].z, efraw[P][2 * j].w,                 \
                       efraw[P][2 * j + 1].x, efraw[P][2 * j + 1].y,         \
                       efraw[P][2 * j + 1].z, efraw[P][2 * j + 1].w};        \
        efp[j] = pack8(f_);                                                  \
      }                                                                      \
    }                                                                        \
    f32x16 acc0, acc1;                                                       \
    _Pragma("unroll")                                                        \
    for (int r = 0; r < 16; r++) { acc0[r] = b0; acc1[r] = b1; }             \
    _Pragma("unroll")                                                        \
    for (int ks = 0; ks < 4; ks++) {                                         \
      bf16x8 av = __builtin_bit_cast(bf16x8, efp[ks]);                       \
      int bi = (ks * 2 + kg) * 64;                                           \
      acc0 = __builtin_amdgcn_mfma_f32_32x32x16_bf16(                        \
          av, __builtin_bit_cast(bf16x8, sb4[bi + col0]), acc0, 0, 0, 0);    \
      acc1 = __builtin_amdgcn_mfma_f32_32x32x16_bf16(                        \
          av, __builtin_bit_cast(bf16x8, sb4[bi + col1]), acc1, 0, 0, 0);    \
    }                                                                        \
    _Pragma("unroll")                                                        \
    for (int ks = 4; ks < 8; ks++) {                                         \
      bf16x8 av = __builtin_bit_cast(bf16x8, sfr[P][ks - 4]);                \
      int bi = (ks * 2 + kg) * 64;                                           \
      acc0 = __builtin_amdgcn_mfma_f32_32x32x16_bf16(                        \
          av, __builtin_bit_cast(bf16x8, sb4[bi + col0]), acc0, 0, 0, 0);    \
      acc1 = __builtin_amdgcn_mfma_f32_32x32x16_bf16(                        \
          av, __builtin_bit_cast(bf16x8, sb4[bi + col1]), acc1, 0, 0, 0);    \
    }                                                                        \
    _Pragma("unroll")                                                        \
    for (int ks = 8; ks < 12; ks++) {                                        \
      bf16x8 av = __builtin_bit_cast(bf16x8, tfr[P][ks - 8]);                \
      int bi = (ks * 2 + kg) * 64;                                           \
      acc0 = __builtin_amdgcn_mfma_f32_32x32x16_bf16(                        \
          av, __builtin_bit_cast(bf16x8, sb4[bi + col0]), acc0, 0, 0, 0);    \
      acc1 = __builtin_amdgcn_mfma_f32_32x32x16_bf16(                        \
          av, __builtin_bit_cast(bf16x8, sb4[bi + col1]), acc1, 0, 0, 0);    \
    }                                                                        \
    float dot = 0.f, n1 = 0.f, n2 = 0.f;                                     \
    u32x4 dfr[4];                                                            \
    _Pragma("unroll")                                                        \
    for (int j = 0; j < 4; j++) {                                            \
      float fs[8], ft[8], fd[8];                                             \
      _Pragma("unroll")                                                      \
      for (int q = 0; q < 4; q++) {                                          \
        fs[2 * q] = bflo(sfr[P][j][q]); fs[2 * q + 1] = bfhi(sfr[P][j][q]);  \
        ft[2 * q] = bflo(tfr[P][j][q]); ft[2 * q + 1] = bfhi(tfr[P][j][q]);  \
      }                                                                      \
      _Pragma("unroll")                                                      \
      for (int c = 0; c < 8; c++) {                                          \
        dot = fmaf(fs[c], ft[c], dot);                                       \
        n1 = fmaf(fs[c], fs[c], n1);                                         \
        n2 = fmaf(ft[c], ft[c], n2);                                         \
        fd[c] = fabsf(fs[c] - ft[c]);                                        \
      }                                                                      \
      dfr[j] = pack8(fd);                                                    \
    }                                                                        \
    _Pragma("unroll")                                                        \
    for (int ks = 12; ks < 16; ks++) {                                       \
      bf16x8 av = __builtin_bit_cast(bf16x8, dfr[ks - 12]);                  \
      int bi = (ks * 2 + kg) * 64;                                           \
      acc0 = __builtin_amdgcn_mfma_f32_32x32x16_bf16(                        \
          av, __builtin_bit_cast(bf16x8, sb4[bi + col0]), acc0, 0, 0, 0);    \
      acc1 = __builtin_amdgcn_mfma_f32_32x32x16_bf16(                        \
          av, __builtin_bit_cast(bf16x8, sb4[bi + col1]), acc1, 0, 0, 0);    \
    }                                                                        \
    dot += __shfl_xor(dot, 32);                                              \
    n1 += __shfl_xor(n1, 32);                                                \
    n2 += __shfl_xor(n2, 32);                                                \
    float sim = dot / fmaxf(sqrtf(n1) * sqrtf(n2), 1e-8f);                   \
    _Pragma("unroll")                                                        \
    for (int r = 0; r < 16; r++) {                                           \
      int row = (r & 3) + 8 * (r >> 2) + 4 * kg;                             \
      float s = __shfl(sim, row);                                            \
      float o0 = fmaf(s, wv0, acc0[r]);                                      \
      float o1 = fmaf(s, wv1, acc1[r]);                                      \
      size_t base = (size_t)(e0_ + row) * 64;                                \
      if (OUT_BF16) {                                                        \
        unsigned short* ob = (unsigned short*)ef_out;                        \
        ob[base + col0] = __builtin_bit_cast(unsigned short, (__bf16)o0);    \
        ob[base + col1] = __builtin_bit_cast(unsigned short, (__bf16)o1);    \
      } else {                                                               \
        float* of = (float*)ef_out;                                          \
        of[base + col0] = o0;                                                \
        of[base + col1] = o1;                                                \
      }                                                                      \
    }                                                                        \
  }

  LOADT(0, 0)
  #pragma unroll
  for (int k = 0; k < NT_EDGE; k++) {
    if (k + 1 < NT_EDGE) {
      if (k & 1) LOADT(k + 1, 0) else LOADT(k + 1, 1)
    }
    if (k & 1) COMPT(k, 1) else COMPT(k, 0)
  }
#undef LOADT
#undef COMPT
}

extern "C" void kernel_launch(void* const* d_in, const int* in_sizes, int n_in,
                              void* d_out, int out_size, void* d_ws, size_t ws_size,
                              hipStream_t stream) {
  const float* x_in   = (const float*)d_in[0];
  const int*   ei     = (const int*)d_in[1];
  const float* ef_in  = (const float*)d_in[2];
  const float* W_self = (const float*)d_in[3];
  const float* W_nbr  = (const float*)d_in[4];
  const float* b_conv = (const float*)d_in[5];
  const float* W_fc   = (const float*)d_in[6];
  const float* b_fc   = (const float*)d_in[7];
  float* out = (float*)d_out;

  const int* src = ei;
  const int* trg = ei + NE;

  char* ws = (char*)d_ws;
  size_t off = 0;
  float* deg      = (float*)(ws + off); off += (((size_t)NN * 4) + 255) & ~(size_t)255;
  int*   rowstart = (int*)(ws + off);   off += (((size_t)(NN + 1) * 4) + 255) & ~(size_t)255;
  int*   cursor   = (int*)(ws + off);   off += (((size_t)NN * 4) + 255) & ~(size_t)255;
  int*   csr      = (int*)(ws + off);   off += (size_t)NE * 4;
  float* agg      = (float*)(ws + off); off += (size_t)NN * 64 * 4;
  float* x_a      = (float*)(ws + off); off += (size_t)NN * 64 * 4;
  float* x_b      = (float*)(ws + off); off += (size_t)NN * 64 * 4;
  unsigned short* Wt  = (unsigned short*)(ws + off); off += (size_t)NL * 16384 * 2;
  unsigned short* efb = (unsigned short*)(ws + off); off += (size_t)NE * 64 * 2;
  unsigned short* xbm = (unsigned short*)(ws + off); off += (size_t)NN * 64 * 2;

  k_zero<<<(NN + 255) / 256, 256, 0, stream>>>(deg);
  k_deg<<<(NE + 255) / 256, 256, 0, stream>>>(trg, deg);
  k_scan<<<1, 1024, 0, stream>>>(deg, rowstart, cursor);
  k_fill<<<(NE + 255) / 256, 256, 0, stream>>>(src, trg, cursor, csr);
  k_wprep<<<(NL * 16384) / 256, 256, 0, stream>>>(W_fc, Wt);
  k_xmir<<<(NN * 8 + 255) / 256, 256, 0, stream>>>(x_in, xbm);

  const float* xcur = x_in;
  float* xnext = x_a;

  // tiles = NE/32 = 25000; per block: 4 waves x NT_EDGE tiles = 20 -> 1250 blocks
  const int EDGE_BLOCKS = NE / (32 * 4 * NT_EDGE);

  for (int i = 0; i < NL; i++) {
    int relu = (i > 0) ? 1 : 0;
    k_agg<<<(NN * 8 + 255) / 256, 256, 0, stream>>>(xbm, rowstart, csr, agg, relu);
    k_conv<<<NN / 4, 256, 0, stream>>>(xcur, agg,
                                       W_self + (size_t)i * 4096,
                                       W_nbr + (size_t)i * 4096,
                                       b_conv + (size_t)i * 64,
                                       xnext, xbm, relu);
    const unsigned short* Wti = Wt + (size_t)i * 16384;
    const float* w256 = W_fc + ((size_t)i * 257 + 256) * 64;
    const float* bfc = b_fc + (size_t)i * 64;
    if (i == 0) {
      k_edge<0, 1><<<EDGE_BLOCKS, 256, 0, stream>>>(xbm, src, trg, ef_in,
                                                    Wti, w256, bfc, efb);
    } else if (i == 1) {
      k_edge<1, 1><<<EDGE_BLOCKS, 256, 0, stream>>>(xbm, src, trg, efb,
                                                    Wti, w256, bfc, efb);
    } else {
      k_edge<1, 0><<<EDGE_BLOCKS, 256, 0, stream>>>(xbm, src, trg, efb,
                                                    Wti, w256, bfc, out);
    }
    xcur = xnext;
    xnext = (xnext == x_a) ? x_b : x_a;
  }
}